// Round 3
// baseline (182.282 us; speedup 1.0000x reference)
//
#include <hip/hip_runtime.h>

// 3x3 median blur + residual, zero padding, x:(8,3,1024,1024) f32.
// Strip kernel, 16 output rows/block, 4 px/thread, 3-deep row prefetch
// pipeline held entirely in registers (launch_bounds caps VGPR at 128 so
// the compiler keeps loads in flight instead of squeezing to 32 VGPRs).

#define S2(a, b) { float _t = fminf(a, b); b = fmaxf(a, b); a = _t; }

__device__ __forceinline__ float med3f(float a, float b, float c) {
    return fmaxf(fminf(a, b), fminf(fmaxf(a, b), c));
}

constexpr int ROWS = 16;   // output rows per block (1024 % 16 == 0)

struct Row { float v[6]; };

__global__ __launch_bounds__(256, 4) void median_blur_kernel(
    const float* __restrict__ xin, float* __restrict__ out)
{
    const int W = 1024, H = 1024;
    const int tx = threadIdx.x;
    const int x0 = tx << 2;                 // 4 px per thread
    const int y0 = blockIdx.x * ROWS;
    const size_t plane = (size_t)blockIdx.y * H * W;
    const float* base  = xin + plane;
    float*       obase = out + plane;

    // clamped halo columns + edge kill flags (branchless, loads stay in bounds)
    const int  xl = (x0 > 0)     ? x0 - 1 : 0;
    const int  xr = (x0 + 4 < W) ? x0 + 4 : W - 1;
    const bool lz = (x0 == 0);
    const bool rz = (x0 + 4 >= W);

    auto load_row = [&](int y, Row& d) {
        if ((unsigned)y < (unsigned)H) {
            const float* row = base + (size_t)y * W;
            const float4 c = *reinterpret_cast<const float4*>(row + x0);
            const float  l = row[xl];       // same cache lines as neighbors' c
            const float  r = row[xr];
            d.v[0] = lz ? 0.0f : l;
            d.v[1] = c.x; d.v[2] = c.y; d.v[3] = c.z; d.v[4] = c.w;
            d.v[5] = rz ? 0.0f : r;
        } else {
#pragma unroll
            for (int j = 0; j < 6; ++j) d.v[j] = 0.0f;
        }
    };

    // prime a 3-deep pipeline: window rows (t,m,b) + 2 prefetched rows
    Row t, m, b, p0, p1;
    load_row(y0 - 1, t);
    load_row(y0,     m);
    load_row(y0 + 1, b);
    load_row(y0 + 2, p0);
    load_row(y0 + 3, p1);

#pragma unroll
    for (int r = 0; r < ROWS; ++r) {
        // issue next load 3 iterations ahead of its use as `b`.
        // rows past y0+ROWS are never used as `b` -> skip (zeros).
        Row nx;
        {
            const int yn = (r <= ROWS - 4) ? (y0 + r + 4) : H;  // H -> zeros
            load_row(yn, nx);
        }

        // vertical sort of the 6 columns
        float lo[6], mi[6], hi[6];
#pragma unroll
        for (int j = 0; j < 6; ++j) {
            float a = t.v[j], c0 = m.v[j], d = b.v[j];
            S2(a, c0); S2(c0, d); S2(a, c0);
            lo[j] = a; mi[j] = c0; hi[j] = d;
        }

        // median of 9 = med3(max of col-mins, med of col-meds, min of col-maxes)
        float4 o; float* op = &o.x;
#pragma unroll
        for (int j = 0; j < 4; ++j) {
            float mxlo = fmaxf(lo[j], fmaxf(lo[j + 1], lo[j + 2]));
            float mnhi = fminf(hi[j], fminf(hi[j + 1], hi[j + 2]));
            float mdmi = med3f(mi[j], mi[j + 1], mi[j + 2]);
            float med  = med3f(mxlo, mdmi, mnhi);
            float xc   = m.v[j + 1];
            op[j] = xc + 0.2f * (med - xc);
        }
        *reinterpret_cast<float4*>(obase + (size_t)(y0 + r) * W + x0) = o;

        // rotate the pipeline (fully unrolled -> pure register renaming)
        t = m; m = b; b = p0; p0 = p1; p1 = nx;
    }
}

extern "C" void kernel_launch(void* const* d_in, const int* in_sizes, int n_in,
                              void* d_out, int out_size, void* d_ws, size_t ws_size,
                              hipStream_t stream) {
    const float* x = (const float*)d_in[0];
    float* out = (float*)d_out;
    const int H = 1024, W = 1024;
    const int planes = in_sizes[0] / (H * W);   // 24
    dim3 block(256);
    dim3 grid(H / ROWS, planes);                // 64 x 24 = 1536 blocks
    median_blur_kernel<<<grid, block, 0, stream>>>(x, out);
}

// Round 4
// 180.581 us; speedup vs baseline: 1.0094x; 1.0094x over previous
//
#include <hip/hip_runtime.h>

// 3x3 median blur + residual, zero padding, x:(8,3,1024,1024) f32.
// Async-LDS pipeline: global_load_lds (fire-and-forget, no dest VGPR) stages
// rows into a 6-row LDS ring, 5 stages in flight, manual vmcnt + raw barrier
// (NOT __syncthreads -> avoids the compiler's vmcnt(0) full drain).
// Global pattern is copy-identical: 1 coalesced dwordx4 per thread per row.

typedef float v4f __attribute__((ext_vector_type(4)));

#define S2(a,b) { float _t=fminf(a,b); (b)=fmaxf(a,b); (a)=_t; }
__device__ __forceinline__ float med3f(float a,float b,float c){
    return fmaxf(fminf(a,b), fminf(fmaxf(a,b),c));
}

constexpr int W = 1024, H = 1024;
constexpr int ROWS = 16;   // output rows per block
constexpr int NBUF = 6;    // LDS row ring (>= pipeline depth 5 + 1)

__global__ __launch_bounds__(256) void median_blur_kernel(
    const float* __restrict__ xin, float* __restrict__ out)
{
    __shared__ float smem[NBUF * W];           // 24 KB
    const int tx = threadIdx.x;
    const int x0 = tx << 2;                    // 4 px per thread
    const int y0 = blockIdx.x * ROWS;
    const size_t plane = (size_t)blockIdx.y * H * W;
    const float* base  = xin + plane;
    float*       obase = out + plane;

    const int  il = (x0 > 0)     ? x0 - 1 : 0; // clamped halo indices (LDS)
    const int  ir = (x0 + 4 < W) ? x0 + 4 : W - 1;
    const bool lz = (x0 == 0), rz = (x0 + 4 >= W);

    // stage s holds image row y0-1+s (clamped; clamped rows' content unused)
    auto issue = [&](int s) {
        int y = y0 - 1 + s;
        y = y < 0 ? 0 : (y > H - 1 ? H - 1 : y);
        const float* g = base + (size_t)y * W + x0;
        float* l = &smem[(s % NBUF) * W + x0];
        __builtin_amdgcn_global_load_lds(
            (const __attribute__((address_space(1))) void*)g,
            (__attribute__((address_space(3))) void*)l, 16, 0, 0);
    };

    // prologue: 5 stages in flight
    issue(0); issue(1); issue(2); issue(3); issue(4);

    auto readrow = [&](int s, bool valid, float* d) {
        if (valid) {                            // block-uniform branch
            const float* sm = &smem[(s % NBUF) * W];
            v4f c = *reinterpret_cast<const v4f*>(sm + x0);
            float l = sm[il], r = sm[ir];
            d[0] = lz ? 0.0f : l;
            d[1] = c.x; d[2] = c.y; d[3] = c.z; d[4] = c.w;
            d[5] = rz ? 0.0f : r;
        } else {
#pragma unroll
            for (int j = 0; j < 6; ++j) d[j] = 0.0f;
        }
    };

    auto compute_store = [&](int r, const float* t, const float* m, const float* b) {
        float lo[6], mi[6], hi[6];
#pragma unroll
        for (int j = 0; j < 6; ++j) {           // vertical sort of 6 columns
            float a = t[j], c0 = m[j], d = b[j];
            S2(a, c0); S2(c0, d); S2(a, c0);
            lo[j] = a; mi[j] = c0; hi[j] = d;
        }
        v4f o;
#pragma unroll
        for (int j = 0; j < 4; ++j) {
            float mxlo = fmaxf(lo[j], fmaxf(lo[j + 1], lo[j + 2]));
            float mnhi = fminf(hi[j], fminf(hi[j + 1], hi[j + 2]));
            float mdmi = med3f(mi[j], mi[j + 1], mi[j + 2]);
            float med  = med3f(mxlo, mdmi, mnhi);
            float xc   = m[j + 1];
            o[j] = xc + 0.2f * (med - xc);
        }
        __builtin_nontemporal_store(o, (v4f*)(obase + (size_t)(y0 + r) * W + x0));
    };

    // iter r: consume stages r,r+1,r+2; issue stage r+5.
    // wait vmcnt(N): N = min(2, 15-r) outstanding allowed -> stage r+2 done.
    // raw s_barrier + asm fences: keep the compiler from draining vmcnt(0)
    // (the __syncthreads pitfall) or reordering LDS ops across the barrier.
#define ITER(R, VM) {                                                   \
    asm volatile("" ::: "memory");                                      \
    __builtin_amdgcn_s_waitcnt(0xF70 | (VM));                           \
    __builtin_amdgcn_s_barrier();                                       \
    asm volatile("" ::: "memory");                                      \
    float t[6], mm[6], bb[6];                                           \
    readrow((R),     y0 + (R) - 1 >= 0, t);                             \
    readrow((R) + 1, true,              mm);                            \
    readrow((R) + 2, y0 + (R) + 1 < H,  bb);                            \
    if ((R) + 5 <= ROWS + 1) issue((R) + 5);                            \
    compute_store((R), t, mm, bb);                                      \
}

    ITER(0, 2)  ITER(1, 2)  ITER(2, 2)  ITER(3, 2)
    ITER(4, 2)  ITER(5, 2)  ITER(6, 2)  ITER(7, 2)
    ITER(8, 2)  ITER(9, 2)  ITER(10, 2) ITER(11, 2)
    ITER(12, 2) ITER(13, 2) ITER(14, 1) ITER(15, 0)
#undef ITER
}

extern "C" void kernel_launch(void* const* d_in, const int* in_sizes, int n_in,
                              void* d_out, int out_size, void* d_ws, size_t ws_size,
                              hipStream_t stream) {
    const float* x = (const float*)d_in[0];
    float* out = (float*)d_out;
    const int planes = in_sizes[0] / (H * W);   // 24
    dim3 block(256);
    dim3 grid(H / ROWS, planes);                // 64 x 24 = 1536 blocks, 6/CU
    median_blur_kernel<<<grid, block, 0, stream>>>(x, out);
}